// Round 5
// baseline (310.422 us; speedup 1.0000x reference)
//
#include <hip/hip_runtime.h>

// Fully fused: out = wpw · depthwise3x3( bilinear_up(x) )  — single kernel.
// Tile: 2 out-rows x 160 cols x 128 cout per block; 512 thr.
// 16 half-chunk phases (16 cin each); triple-buffered DMA staging with
// counted vmcnt(2) (depth-2 pipeline, m201-style raw barriers); wpw A-frags
// preloaded to regs; wdw x row-interp folded once in prologue; LDS-transpose
// epilogue for contiguous 320B NT stores.
#define CIN  256
#define HIN  60
#define WIN  80
#define UPH  120
#define UPW  160
#define COUT 128
#define NPIX (UPH*UPW)   // 19200

typedef __bf16 bf16x8 __attribute__((ext_vector_type(8)));
typedef float  floatx4 __attribute__((ext_vector_type(4)));

#define F_NT  512
#define NPH   16        // half-chunk phases, 16 ch each
#define GPC   48        // 16B-granules per ch: 4 rows x 12 quads (q=11 pad)
#define NG    768       // granules per phase = 16ch x 48
#define XFB   12288     // bytes per s_xf buffer (768 x 16)

// LDS carve (single char arena; epilogue reuses [0,43008) = s_xf+part of s_dw)
#define OFF_XF    0          // 3 x 12288 = 36864
#define OFF_DW    36864      // 160 px x 40 shorts x 2B = 12800
#define OFF_A     49664      // 256 ch x 18 x 4B = 18432
#define OFF_RW    68096      // 18 x 4B = 72  (pad to 80)
#define OFF_SCRAP 68176      // 1024B dummy-DMA target
#define SMEM_SZ   69200

#define FENCE __builtin_amdgcn_sched_barrier(0)

__global__ __launch_bounds__(F_NT, 4) void fused_kernel(
    const float* __restrict__ x,      // [8,256,60,80]
    const float* __restrict__ wdw,    // [256,1,3,3]
    const float* __restrict__ wpw,    // [128,256]
    float* __restrict__ out)          // [8,128,120,160]
{
    __shared__ __align__(16) char smem[SMEM_SZ];
    float*  s_rw = (float*)(smem + OFF_RW);
    float*  s_A  = (float*)(smem + OFF_A);
    __bf16* s_dw = (__bf16*)(smem + OFF_DW);

    const int tid = threadIdx.x;

    // XCD-bijective swizzle: 960 = 8 XCDs x 120; XCD k = image k, rows ascend
    const int bid = blockIdx.x;
    const int wg  = (bid & 7) * 120 + (bid >> 3);
    const int wt  = wg & 1;
    const int t2  = wg >> 1;
    const int ht  = t2 % 60;
    const int b   = t2 / 60;

    const int h0 = ht * 2, w0 = wt * 80;
    const float HS = 59.0f / 121.0f, WS = 79.0f / 161.0f;
    const int rbase = (int)((float)h0 * HS);
    const int c0a   = ((int)((float)w0 * WS)) & ~3;      // 0 or 36

    // ---- block-invariant row-interp weights rw[ahh*9 + i3*3 + dy] ----
    if (tid < 18) {
        int ahh = tid / 9, t = tid - ahh * 9;
        int i3 = t / 3, dy = t - i3 * 3;
        int ybh = (int)((float)(h0 + ahh) * HS);
        float hy = (float)(h0 + ahh + i3) * HS;
        int y0 = (int)hy; float fy = hy - (float)y0;
        int y1 = min(y0 + 1, HIN - 1);
        s_rw[tid] = ((y0 - ybh) == dy ? 1.f - fy : 0.f)
                  + ((y1 - ybh) == dy ? fy : 0.f);
    }

    const int lane = tid & 63, wave = tid >> 6;
    const int quad = lane >> 4, l16 = lane & 15;

    // gather decode: lanes sweep columns (bank-friendly); 2 ch per wave
    const int chl = tid >> 5;            // 0..15 ch-local in half-chunk
    const int g   = (tid >> 4) & 1;      // 5-px group
    const int hh  = (tid >> 3) & 1;      // out-row
    const int s   = tid & 7;             // 10-px segment
    const int rbh = (int)((float)(h0 + hh) * HS) - rbase;   // 0 or 1

    const float* xb = x + (size_t)b * CIN * (HIN * WIN);

    // ---- wpw A-frag preload: 8 chunks x bf16x8 (32 VGPR), no vmem in loop ----
    bf16x8 af[8];
    #pragma unroll
    for (int c = 0; c < 8; ++c) {
        const float* wr = wpw + (size_t)(wave * 16 + l16) * CIN + c * 32 + quad * 8;
        float4 v0 = *(const float4*)wr;
        float4 v1 = *(const float4*)(wr + 4);
        af[c] = (bf16x8){(__bf16)v0.x,(__bf16)v0.y,(__bf16)v0.z,(__bf16)v0.w,
                         (__bf16)v1.x,(__bf16)v1.y,(__bf16)v1.z,(__bf16)v1.w};
    }

    __syncthreads();   // BAR0: s_rw visible (before any DMA in flight)

    // ---- fold ALL 256ch A-weights once: 4608 items = 9/thread ----
    #pragma unroll
    for (int k = 0; k < 9; ++k) {
        int i = tid + k * F_NT;
        int gch = i / 18, t = i - gch * 18;
        int h2 = t / 9, t9 = t - h2 * 9, dy = t9 / 3, j = t9 - dy * 3;
        const float* wp = wdw + gch * 9 + j;
        s_A[gch * 18 + t] = s_rw[h2*9 + dy]     * wp[0]
                          + s_rw[h2*9 + 3 + dy] * wp[3]
                          + s_rw[h2*9 + 6 + dy] * wp[6];
    }

    // ---- async DMA: 12 real instrs + 4 dummies -> every wave issues exactly 2
    auto dma = [&](int cb, char* dst) {
        {   // slot 0: granules [wave*64, wave*64+64)
            int it = wave * 64 + lane;
            int c = it / GPC, t = it - c * GPC;
            int r = t / 12, q = t - r * 12; q = min(q, 10);
            const float* src = xb + (size_t)(cb + c) * (HIN * WIN)
                             + min(rbase + r, HIN - 1) * WIN + c0a + q * 4;
            __builtin_amdgcn_global_load_lds(
                (const __attribute__((address_space(1))) void*)src,
                (__attribute__((address_space(3))) void*)(dst + (size_t)(wave * 64) * 16),
                16, 0, 0);
        }
        {   // slot 1: granules [512 + (wave&3)*64, +64); waves 4-7 -> scrap
            int it = 512 + (wave & 3) * 64 + lane;
            int c = it / GPC, t = it - c * GPC;
            int r = t / 12, q = t - r * 12; q = min(q, 10);
            const float* src = xb + (size_t)(cb + c) * (HIN * WIN)
                             + min(rbase + r, HIN - 1) * WIN + c0a + q * 4;
            char* d = (wave < 4) ? (dst + (size_t)(512 + (wave & 3) * 64) * 16)
                                 : (smem + OFF_SCRAP);
            __builtin_amdgcn_global_load_lds(
                (const __attribute__((address_space(1))) void*)src,
                (__attribute__((address_space(3))) void*)d,
                16, 0, 0);
        }
    };

    floatx4 acc[10];
    #pragma unroll
    for (int n = 0; n < 10; ++n) acc[n] = (floatx4){0.f, 0.f, 0.f, 0.f};

    // prologue fill: DMA(0), DMA(1)  (issued LAST -> only DMAs outstanding)
    dma(0, smem + OFF_XF);
    dma(16, smem + OFF_XF + XFB);

    #pragma unroll
    for (int h = 0; h < NPH; ++h) {
        // BAR_a: retire DMA(h) (counted — DMA(h+1) stays in flight),
        //        drain own ds ops (prev gather reads / MFMA b128 reads)
        if (h < NPH - 1) asm volatile("s_waitcnt lgkmcnt(0) vmcnt(2)" ::: "memory");
        else             asm volatile("s_waitcnt lgkmcnt(0) vmcnt(0)" ::: "memory");
        FENCE; __builtin_amdgcn_s_barrier(); FENCE;

        // issue DMA(h+2) (safe: gather(h-1) reads of this buffer drained above)
        if (h + 2 < NPH) dma((h + 2) * 16, smem + OFF_XF + ((h + 2) % 3) * XFB);

        // ---- gather + depthwise: 5 px for (chl, g, hh, s) ----
        const float* xf = (const float*)(smem + OFF_XF + (h % 3) * XFB);
        const float* Ab = s_A + (h * 16 + chl) * 18 + hh * 9;
        float Ar[3][3];
        #pragma unroll
        for (int dy = 0; dy < 3; ++dy)
            #pragma unroll
            for (int j = 0; j < 3; ++j) Ar[dy][j] = Ab[dy * 3 + j];

        const int ub = w0 + s * 10 + g * 5;
        float fx[7]; int ci[7];
        #pragma unroll
        for (int j = 0; j < 7; ++j) {
            float wx = (float)(ub + j) * WS;
            int x0 = (int)wx;
            fx[j] = wx - (float)x0;
            ci[j] = x0 - c0a;
        }
        float d[5] = {0.f, 0.f, 0.f, 0.f, 0.f};
        #pragma unroll
        for (int dy = 0; dy < 3; ++dy) {
            const float* rp = xf + chl * 192 + (rbh + dy) * 48;
            float cx[7];
            #pragma unroll
            for (int j = 0; j < 7; ++j) {
                float lo = rp[ci[j]], hi = rp[ci[j] + 1];
                cx[j] = fmaf(fx[j], hi - lo, lo);
            }
            float A0 = Ar[dy][0], A1 = Ar[dy][1], A2 = Ar[dy][2];
            #pragma unroll
            for (int i = 0; i < 5; ++i)
                d[i] = fmaf(A0, cx[i], fmaf(A1, cx[i+1], fmaf(A2, cx[i+2], d[i])));
        }
        {   // write dw tile [px][k] with quad-group XOR swizzle
            const int kk = (h & 1) * 16 + chl;          // k index 0..31
            const int kg = kk >> 3, kl = kk & 7;
            #pragma unroll
            for (int i = 0; i < 5; ++i) {
                int px = hh * 80 + s * 10 + g * 5 + i;
                s_dw[px * 40 + ((kg ^ (px & 3)) << 3) + kl] = (__bf16)d[i];
            }
        }

        if (h & 1) {   // full 32-ch chunk ready -> MFMA
            asm volatile("s_waitcnt lgkmcnt(0)" ::: "memory");
            FENCE; __builtin_amdgcn_s_barrier(); FENCE;
            const int c = h >> 1;   // compile-time (full unroll) -> af[c] static
            #pragma unroll
            for (int n = 0; n < 10; ++n) {
                const __bf16* bp = s_dw + (n * 16 + l16) * 40
                                 + ((quad ^ (l16 & 3)) << 3);
                bf16x8 bf = *(const bf16x8*)bp;
                acc[n] = __builtin_amdgcn_mfma_f32_16x16x32_bf16(af[c], bf, acc[n], 0, 0, 0);
            }
        }
    }

    // ---- epilogue: LDS transpose -> contiguous 320B NT row stores ----
    asm volatile("s_waitcnt lgkmcnt(0)" ::: "memory");
    FENCE; __builtin_amdgcn_s_barrier(); FENCE;

    float* tb = (float*)smem;              // 128 x 84 floats = 43008 B
    const int rr = tid >> 2, sg = tid & 3;
    #pragma unroll
    for (int rowl = 0; rowl < 2; ++rowl) {
        #pragma unroll
        for (int n = 0; n < 5; ++n)
            #pragma unroll
            for (int e = 0; e < 4; ++e)
                tb[(wave * 16 + quad * 4 + e) * 84 + n * 16 + l16] = acc[rowl * 5 + n][e];

        asm volatile("s_waitcnt lgkmcnt(0)" ::: "memory");
        FENCE; __builtin_amdgcn_s_barrier(); FENCE;

        float* op = out + (size_t)(b * COUT + rr) * NPIX
                  + (size_t)(h0 + rowl) * UPW + w0 + sg * 20;
        #pragma unroll
        for (int i = 0; i < 5; ++i) {
            floatx4 v = *(const floatx4*)&tb[rr * 84 + sg * 20 + i * 4];
            __builtin_nontemporal_store(v, (floatx4*)(op + i * 4));
        }

        asm volatile("s_waitcnt lgkmcnt(0)" ::: "memory");
        FENCE; __builtin_amdgcn_s_barrier(); FENCE;
    }
}

extern "C" void kernel_launch(void* const* d_in, const int* in_sizes, int n_in,
                              void* d_out, int out_size, void* d_ws, size_t ws_size,
                              hipStream_t stream)
{
    (void)d_ws; (void)ws_size;
    const float* x   = (const float*)d_in[0];
    const float* wdw = (const float*)d_in[1];
    const float* wpw = (const float*)d_in[2];

    fused_kernel<<<dim3(960), F_NT, 0, stream>>>(x, wdw, wpw, (float*)d_out);
}

// Round 6
// 294.991 us; speedup vs baseline: 1.0523x; 1.0523x over previous
//
#include <hip/hip_runtime.h>

// Fully fused: out = wpw · depthwise3x3( bilinear_up(x) ) — single kernel.
// Tile: 1 out-row x 80 cols x 128 cout (acc=20 regs/thread -> spill-free).
// 8 K-phases of 32 cin; triple-buffered global_load_lds with counted vmcnt(3)
// (depth-2); wpw A-frags preloaded (zero loop vmem); LDS-transpose epilogue.
#define CIN  256
#define HIN  60
#define WIN  80
#define UPH  120
#define UPW  160
#define COUT 128
#define NPIX (UPH*UPW)   // 19200

typedef __bf16 bf16x8 __attribute__((ext_vector_type(8)));
typedef float  floatx4 __attribute__((ext_vector_type(4)));

#define F_NT 512
#define KC   32            // cin per phase
#define NPH  8
#define GPC  36            // granules/ch = 3 rows x 12 quads (16B each)
#define NG   (KC*GPC)      // 1152 granules per phase
#define XFB  (NG*16)       // 18432 B per staging buffer
#define CHW  144           // floats per staged ch
#define RWD  48            // floats per staged row

#define OFF_XF    0                    // 3 x 18432 = 55296
#define OFF_DW    55296                // 80 px x 40 sh x 2B = 6400
#define OFF_A     61696                // 256 x 9 x 4B = 9216
#define OFF_SCRAP 70912                // 1024 B dummy-DMA target
#define SMEM_SZ   71936

#define FENCE __builtin_amdgcn_sched_barrier(0)

__global__ __launch_bounds__(F_NT, 4) void fused_kernel(
    const float* __restrict__ x,      // [8,256,60,80]
    const float* __restrict__ wdw,    // [256,1,3,3]
    const float* __restrict__ wpw,    // [128,256]
    float* __restrict__ out)          // [8,128,120,160]
{
    __shared__ __align__(16) char smem[SMEM_SZ];
    float*  s_A  = (float*)(smem + OFF_A);
    __bf16* s_dw = (__bf16*)(smem + OFF_DW);

    const int tid = threadIdx.x;

    // XCD-bijective swizzle: 1920 = 8 XCDs x 240; XCD k = image k, rows ascend
    const int bid = blockIdx.x;
    const int b   = bid & 7;
    const int r2  = bid >> 3;          // 0..239
    const int h0  = r2 >> 1;           // out row 0..119
    const int w0  = (r2 & 1) * 80;

    const float HS = 59.0f / 121.0f, WS = 79.0f / 161.0f;
    const int rbase = (int)((float)h0 * HS);
    const int c0a   = ((int)((float)w0 * WS)) & ~3;     // 0 or 36

    const int lane = tid & 63, wave = tid >> 6;
    const int quad = lane >> 4, l16 = lane & 15;

    // gather decode: ch-local (32) x 5-px segment (16)
    const int ch  = tid >> 4;
    const int seg = tid & 15;

    const float* xb = x + (size_t)b * CIN * (HIN * WIN);

    // ---- row-interp weights (regs, uniform per block) ----
    float rw[9];
    #pragma unroll
    for (int i3 = 0; i3 < 3; ++i3) {
        float hy = (float)(h0 + i3) * HS;
        int y0 = (int)hy; float fy = hy - (float)y0;
        int y1 = min(y0 + 1, HIN - 1);
        #pragma unroll
        for (int dy = 0; dy < 3; ++dy)
            rw[i3 * 3 + dy] = ((y0 - rbase) == dy ? 1.f - fy : 0.f)
                            + ((y1 - rbase) == dy ? fy : 0.f);
    }

    // ---- wpw A-frag preload: 8 phases x bf16x8 (32 VGPR); zero loop vmem ----
    bf16x8 af[8];
    #pragma unroll
    for (int c = 0; c < 8; ++c) {
        const float* wr = wpw + (size_t)(wave * 16 + l16) * CIN + c * KC + quad * 8;
        float4 v0 = *(const float4*)wr;
        float4 v1 = *(const float4*)(wr + 4);
        af[c] = (bf16x8){(__bf16)v0.x,(__bf16)v0.y,(__bf16)v0.z,(__bf16)v0.w,
                         (__bf16)v1.x,(__bf16)v1.y,(__bf16)v1.z,(__bf16)v1.w};
    }

    // ---- fold all 256ch A-weights: A[ch][dy*3+j] = sum_i3 rw[i3,dy]*wdw[ch,i3,j]
    #pragma unroll
    for (int k = 0; k < 5; ++k) {
        int i = tid + k * F_NT;
        if (i < CIN * 9) {
            int gch = i / 9, t = i - gch * 9;
            int dy = t / 3, j = t - dy * 3;
            const float* wp = wdw + gch * 9 + j;
            s_A[gch * 9 + t] = rw[dy] * wp[0] + rw[3 + dy] * wp[3] + rw[6 + dy] * wp[6];
        }
    }

    // ---- phase-invariant col-interp state ----
    float fx[7]; int ci[7];
    #pragma unroll
    for (int j = 0; j < 7; ++j) {
        float wx = (float)(w0 + seg * 5 + j) * WS;
        int x0 = (int)wx;
        fx[j] = wx - (float)x0;
        ci[j] = x0 - c0a;
    }

    // ---- async DMA: exactly 3 global_load_lds per wave per phase ----
    auto dma = [&](int cb, char* dst) {
        #pragma unroll
        for (int slt = 0; slt < 3; ++slt) {
            int gb; char* db;
            if (slt < 2)      { gb = slt * 512 + wave * 64;       db = dst + gb * 16; }
            else if (wave < 2){ gb = 1024 + wave * 64;            db = dst + gb * 16; }
            else              { gb = 1024 + (wave & 1) * 64;      db = smem + OFF_SCRAP; }
            int it = gb + lane;
            int c = it / GPC, t = it - c * GPC;
            int r = t / 12, q = t - r * 12; q = min(q, 10);
            const float* src = xb + (size_t)(cb + c) * (HIN * WIN)
                             + min(rbase + r, HIN - 1) * WIN + c0a + q * 4;
            __builtin_amdgcn_global_load_lds(
                (const __attribute__((address_space(1))) void*)src,
                (__attribute__((address_space(3))) void*)db, 16, 0, 0);
        }
    };

    floatx4 acc[5];
    #pragma unroll
    for (int n = 0; n < 5; ++n) acc[n] = (floatx4){0.f, 0.f, 0.f, 0.f};

    // prologue: all prior vmem retired, then exactly 6 DMAs outstanding
    asm volatile("s_waitcnt vmcnt(0)" ::: "memory");
    dma(0,  smem + OFF_XF);
    dma(KC, smem + OFF_XF + XFB);

    #pragma unroll
    for (int p = 0; p < NPH; ++p) {
        // TOP: retire DMA(p) (DMA(p+1) stays in flight); own ds ops drained;
        //      barrier -> all waves' DMA(p)/stores visible (also covers s_A)
        if (p < NPH - 1) asm volatile("s_waitcnt vmcnt(3) lgkmcnt(0)" ::: "memory");
        else             asm volatile("s_waitcnt vmcnt(0) lgkmcnt(0)" ::: "memory");
        FENCE; __builtin_amdgcn_s_barrier(); FENCE;

        if (p + 2 < NPH) dma((p + 2) * KC, smem + OFF_XF + ((p + 2) % 3) * XFB);

        // ---- gather + depthwise: 5 px for (ch, seg) ----
        const float* xf = (const float*)(smem + OFF_XF + (p % 3) * XFB);
        float Ar[9];
        #pragma unroll
        for (int t = 0; t < 9; ++t) Ar[t] = s_A[(p * KC + ch) * 9 + t];

        float d[5] = {0.f, 0.f, 0.f, 0.f, 0.f};
        #pragma unroll
        for (int dy = 0; dy < 3; ++dy) {
            const float* rp = xf + ch * CHW + dy * RWD;
            float cx[7];
            #pragma unroll
            for (int j = 0; j < 7; ++j) {
                float lo = rp[ci[j]], hi = rp[ci[j] + 1];
                cx[j] = fmaf(fx[j], hi - lo, lo);
            }
            float A0 = Ar[dy * 3], A1 = Ar[dy * 3 + 1], A2 = Ar[dy * 3 + 2];
            #pragma unroll
            for (int i = 0; i < 5; ++i)
                d[i] = fmaf(A0, cx[i], fmaf(A1, cx[i+1], fmaf(A2, cx[i+2], d[i])));
        }
        #pragma unroll
        for (int i = 0; i < 5; ++i) {
            int px = seg * 5 + i;
            s_dw[px * 40 + (((ch >> 3) ^ (px & 3)) << 3) + (ch & 7)] = (__bf16)d[i];
        }

        // MID: dw tile visible; MFMA (reads s_dw only; DMA(p+1..p+2) in flight)
        asm volatile("s_waitcnt lgkmcnt(0)" ::: "memory");
        FENCE; __builtin_amdgcn_s_barrier(); FENCE;

        #pragma unroll
        for (int n = 0; n < 5; ++n) {
            const __bf16* bp = s_dw + (n * 16 + l16) * 40 + ((quad ^ (l16 & 3)) << 3);
            bf16x8 bfr = *(const bf16x8*)bp;
            acc[n] = __builtin_amdgcn_mfma_f32_16x16x32_bf16(af[p], bfr, acc[n], 0, 0, 0);
        }
    }

    // ---- epilogue: LDS transpose -> contiguous 320B NT row stores ----
    // (tb region [0,43008) is disjoint from s_dw; all s_xf reads drained at MID(7))
    float* tb = (float*)smem;   // [128 cout][84] floats
    #pragma unroll
    for (int n = 0; n < 5; ++n)
        #pragma unroll
        for (int e = 0; e < 4; ++e)
            tb[(wave * 16 + quad * 4 + e) * 84 + n * 16 + l16] = acc[n][e];

    asm volatile("s_waitcnt lgkmcnt(0)" ::: "memory");
    FENCE; __builtin_amdgcn_s_barrier(); FENCE;

    const int rr = tid >> 2, sg = tid & 3;
    float* op = out + (size_t)(b * COUT + rr) * NPIX + (size_t)h0 * UPW + w0 + sg * 20;
    #pragma unroll
    for (int i = 0; i < 5; ++i) {
        floatx4 v = *(const floatx4*)&tb[rr * 84 + sg * 20 + i * 4];
        __builtin_nontemporal_store(v, (floatx4*)(op + i * 4));
    }
}

extern "C" void kernel_launch(void* const* d_in, const int* in_sizes, int n_in,
                              void* d_out, int out_size, void* d_ws, size_t ws_size,
                              hipStream_t stream)
{
    (void)d_ws; (void)ws_size;
    const float* x   = (const float*)d_in[0];
    const float* wdw = (const float*)d_in[1];
    const float* wpw = (const float*)d_in[2];

    fused_kernel<<<dim3(1920), F_NT, 0, stream>>>(x, wdw, wpw, (float*)d_out);
}

// Round 7
// 204.645 us; speedup vs baseline: 1.5169x; 1.4415x over previous
//
#include <hip/hip_runtime.h>

// Fully fused: out = wpw · depthwise3x3( bilinear_up(x) ) — single kernel.
// Tile: 1 out-row x 80 cols x 128 cout (acc=20 regs/thread -> spill-free).
// 8 K-phases of 32 cin; triple-buffered global_load_lds with counted vmcnt(3)
// (depth-2); wpw A-frags preloaded (zero loop vmem); LDS-transpose epilogue
// with SECTOR-COMPLETE NT stores (each instr: 4 lanes x 16B = one 64B sector).
#define CIN  256
#define HIN  60
#define WIN  80
#define UPH  120
#define UPW  160
#define COUT 128
#define NPIX (UPH*UPW)   // 19200

typedef __bf16 bf16x8 __attribute__((ext_vector_type(8)));
typedef float  floatx4 __attribute__((ext_vector_type(4)));

#define F_NT 512
#define KC   32            // cin per phase
#define NPH  8
#define GPC  36            // granules/ch = 3 rows x 12 quads (16B each)
#define NG   (KC*GPC)      // 1152 granules per phase
#define XFB  (NG*16)       // 18432 B per staging buffer
#define CHW  144           // floats per staged ch
#define RWD  48            // floats per staged row

#define OFF_XF    0                    // 3 x 18432 = 55296
#define OFF_DW    55296                // 80 px x 40 sh x 2B = 6400
#define OFF_A     61696                // 256 x 9 x 4B = 9216
#define OFF_SCRAP 70912                // 1024 B dummy-DMA target
#define SMEM_SZ   71936

#define FENCE __builtin_amdgcn_sched_barrier(0)

__global__ __launch_bounds__(F_NT, 4) void fused_kernel(
    const float* __restrict__ x,      // [8,256,60,80]
    const float* __restrict__ wdw,    // [256,1,3,3]
    const float* __restrict__ wpw,    // [128,256]
    float* __restrict__ out)          // [8,128,120,160]
{
    __shared__ __align__(16) char smem[SMEM_SZ];
    float*  s_A  = (float*)(smem + OFF_A);
    __bf16* s_dw = (__bf16*)(smem + OFF_DW);

    const int tid = threadIdx.x;

    // XCD-bijective swizzle: 1920 = 8 XCDs x 240; XCD k = image k, rows ascend
    const int bid = blockIdx.x;
    const int b   = bid & 7;
    const int r2  = bid >> 3;          // 0..239
    const int h0  = r2 >> 1;           // out row 0..119
    const int w0  = (r2 & 1) * 80;

    const float HS = 59.0f / 121.0f, WS = 79.0f / 161.0f;
    const int rbase = (int)((float)h0 * HS);
    const int c0a   = ((int)((float)w0 * WS)) & ~3;     // 0 or 36

    const int lane = tid & 63, wave = tid >> 6;
    const int quad = lane >> 4, l16 = lane & 15;

    // gather decode: ch-local (32) x 5-px segment (16)
    const int ch  = tid >> 4;
    const int seg = tid & 15;

    const float* xb = x + (size_t)b * CIN * (HIN * WIN);

    // ---- row-interp weights (regs, uniform per block) ----
    float rw[9];
    #pragma unroll
    for (int i3 = 0; i3 < 3; ++i3) {
        float hy = (float)(h0 + i3) * HS;
        int y0 = (int)hy; float fy = hy - (float)y0;
        int y1 = min(y0 + 1, HIN - 1);
        #pragma unroll
        for (int dy = 0; dy < 3; ++dy)
            rw[i3 * 3 + dy] = ((y0 - rbase) == dy ? 1.f - fy : 0.f)
                            + ((y1 - rbase) == dy ? fy : 0.f);
    }

    // ---- wpw A-frag preload: 8 phases x bf16x8 (32 VGPR); zero loop vmem ----
    bf16x8 af[8];
    #pragma unroll
    for (int c = 0; c < 8; ++c) {
        const float* wr = wpw + (size_t)(wave * 16 + l16) * CIN + c * KC + quad * 8;
        float4 v0 = *(const float4*)wr;
        float4 v1 = *(const float4*)(wr + 4);
        af[c] = (bf16x8){(__bf16)v0.x,(__bf16)v0.y,(__bf16)v0.z,(__bf16)v0.w,
                         (__bf16)v1.x,(__bf16)v1.y,(__bf16)v1.z,(__bf16)v1.w};
    }

    // ---- fold all 256ch A-weights: A[ch][dy*3+j] = sum_i3 rw[i3,dy]*wdw[ch,i3,j]
    #pragma unroll
    for (int k = 0; k < 5; ++k) {
        int i = tid + k * F_NT;
        if (i < CIN * 9) {
            int gch = i / 9, t = i - gch * 9;
            int dy = t / 3, j = t - dy * 3;
            const float* wp = wdw + gch * 9 + j;
            s_A[gch * 9 + t] = rw[dy] * wp[0] + rw[3 + dy] * wp[3] + rw[6 + dy] * wp[6];
        }
    }

    // ---- phase-invariant col-interp state ----
    float fx[7]; int ci[7];
    #pragma unroll
    for (int j = 0; j < 7; ++j) {
        float wx = (float)(w0 + seg * 5 + j) * WS;
        int x0 = (int)wx;
        fx[j] = wx - (float)x0;
        ci[j] = x0 - c0a;
    }

    // ---- async DMA: exactly 3 global_load_lds per wave per phase ----
    auto dma = [&](int cb, char* dst) {
        #pragma unroll
        for (int slt = 0; slt < 3; ++slt) {
            int gb; char* db;
            if (slt < 2)      { gb = slt * 512 + wave * 64;       db = dst + gb * 16; }
            else if (wave < 2){ gb = 1024 + wave * 64;            db = dst + gb * 16; }
            else              { gb = 1024 + (wave & 1) * 64;      db = smem + OFF_SCRAP; }
            int it = gb + lane;
            int c = it / GPC, t = it - c * GPC;
            int r = t / 12, q = t - r * 12; q = min(q, 10);
            const float* src = xb + (size_t)(cb + c) * (HIN * WIN)
                             + min(rbase + r, HIN - 1) * WIN + c0a + q * 4;
            __builtin_amdgcn_global_load_lds(
                (const __attribute__((address_space(1))) void*)src,
                (__attribute__((address_space(3))) void*)db, 16, 0, 0);
        }
    };

    floatx4 acc[5];
    #pragma unroll
    for (int n = 0; n < 5; ++n) acc[n] = (floatx4){0.f, 0.f, 0.f, 0.f};

    // prologue: all prior vmem retired, then exactly 6 DMAs outstanding
    asm volatile("s_waitcnt vmcnt(0)" ::: "memory");
    dma(0,  smem + OFF_XF);
    dma(KC, smem + OFF_XF + XFB);

    #pragma unroll
    for (int p = 0; p < NPH; ++p) {
        // TOP: retire DMA(p) (DMA(p+1) stays in flight); own ds ops drained;
        //      barrier -> all waves' DMA(p)/stores visible (also covers s_A)
        if (p < NPH - 1) asm volatile("s_waitcnt vmcnt(3) lgkmcnt(0)" ::: "memory");
        else             asm volatile("s_waitcnt vmcnt(0) lgkmcnt(0)" ::: "memory");
        FENCE; __builtin_amdgcn_s_barrier(); FENCE;

        if (p + 2 < NPH) dma((p + 2) * KC, smem + OFF_XF + ((p + 2) % 3) * XFB);

        // ---- gather + depthwise: 5 px for (ch, seg) ----
        const float* xf = (const float*)(smem + OFF_XF + (p % 3) * XFB);
        float Ar[9];
        #pragma unroll
        for (int t = 0; t < 9; ++t) Ar[t] = s_A[(p * KC + ch) * 9 + t];

        float d[5] = {0.f, 0.f, 0.f, 0.f, 0.f};
        #pragma unroll
        for (int dy = 0; dy < 3; ++dy) {
            const float* rp = xf + ch * CHW + dy * RWD;
            float cx[7];
            #pragma unroll
            for (int j = 0; j < 7; ++j) {
                float lo = rp[ci[j]], hi = rp[ci[j] + 1];
                cx[j] = fmaf(fx[j], hi - lo, lo);
            }
            float A0 = Ar[dy * 3], A1 = Ar[dy * 3 + 1], A2 = Ar[dy * 3 + 2];
            #pragma unroll
            for (int i = 0; i < 5; ++i)
                d[i] = fmaf(A0, cx[i], fmaf(A1, cx[i+1], fmaf(A2, cx[i+2], d[i])));
        }
        #pragma unroll
        for (int i = 0; i < 5; ++i) {
            int px = seg * 5 + i;
            s_dw[px * 40 + (((ch >> 3) ^ (px & 3)) << 3) + (ch & 7)] = (__bf16)d[i];
        }

        // MID: dw tile visible; MFMA (reads s_dw only; DMA(p+1..p+2) in flight)
        asm volatile("s_waitcnt lgkmcnt(0)" ::: "memory");
        FENCE; __builtin_amdgcn_s_barrier(); FENCE;

        #pragma unroll
        for (int n = 0; n < 5; ++n) {
            const __bf16* bp = s_dw + (n * 16 + l16) * 40 + ((quad ^ (l16 & 3)) << 3);
            bf16x8 bfr = *(const bf16x8*)bp;
            acc[n] = __builtin_amdgcn_mfma_f32_16x16x32_bf16(af[p], bfr, acc[n], 0, 0, 0);
        }
    }

    // ---- epilogue: LDS transpose -> NT stores, sector-complete per instr ----
    // (tb region [0,43008) is disjoint from s_dw; all s_xf reads drained at MID(7))
    float* tb = (float*)smem;   // [128 cout][84] floats
    #pragma unroll
    for (int n = 0; n < 5; ++n)
        #pragma unroll
        for (int e = 0; e < 4; ++e)
            tb[(wave * 16 + quad * 4 + e) * 84 + n * 16 + l16] = acc[n][e];

    asm volatile("s_waitcnt lgkmcnt(0)" ::: "memory");
    FENCE; __builtin_amdgcn_s_barrier(); FENCE;

    // thread (rr, sg): row rr, stores float4 at q = i*4+sg -> for each instr i,
    // lanes sg=0..3 cover one aligned complete 64B sector (row base 64B-aligned).
    const int rr = tid >> 2, sg = tid & 3;
    float* op = out + (size_t)(b * COUT + rr) * NPIX + (size_t)h0 * UPW + w0;
    #pragma unroll
    for (int i = 0; i < 5; ++i) {
        int q = i * 4 + sg;
        floatx4 v = *(const floatx4*)&tb[rr * 84 + q * 4];
        __builtin_nontemporal_store(v, (floatx4*)(op + q * 4));
    }
}

extern "C" void kernel_launch(void* const* d_in, const int* in_sizes, int n_in,
                              void* d_out, int out_size, void* d_ws, size_t ws_size,
                              hipStream_t stream)
{
    (void)d_ws; (void)ws_size;
    const float* x   = (const float*)d_in[0];
    const float* wdw = (const float*)d_in[1];
    const float* wpw = (const float*)d_in[2];

    fused_kernel<<<dim3(1920), F_NT, 0, stream>>>(x, wdw, wpw, (float*)d_out);
}